// Round 5
// baseline (198.974 us; speedup 1.0000x reference)
//
#include <hip/hip_runtime.h>

#define IN_DIM   256
#define HID_DIM  512
#define OUT_DIM  256
#define N_CHILD  8
#define BATCH    1024

#define SB    16   // samples per chunk
#define PAD   20   // LDS row pad: 16B-aligned 4-groups, conflict-limited writes
#define MAXCH 128  // static bound: sum ceil(n_a/SB) <= (1024+64*15)/16 = 124

// ---------------- prep: counting-sort samples by agent, build chunk list ----
// agent_indices may be int32 or int64 (jax_enable_x64): view as int32; if any
// odd word != 0 it's int32 (odd slots are random agents), else int64 (odd
// slots are zero high words). P(false int64 | int32) = 64^-512 ~ 0.
extern "C" __global__ __launch_bounds__(1024)
void prep_sort(const int* __restrict__ raw, int* __restrict__ sorted,
               int* __restrict__ ch_agent, int* __restrict__ ch_start,
               int* __restrict__ ch_len)
{
    __shared__ int cnt[64], start[64];
    __shared__ int is32;
    const int t = threadIdx.x;
    if (t < 64) cnt[t] = 0;
    if (t == 0) is32 = 0;
    __syncthreads();
    if (raw[2 * (t & 511) + 1] != 0) is32 = 1;   // benign shared race
    __syncthreads();
    const int a = (is32 ? raw[t] : raw[2 * t]) & 63;
    atomicAdd(&cnt[a], 1);
    __syncthreads();
    if (t == 0) {
        int off = 0, nch = 0;
        for (int i = 0; i < 64; ++i) {
            start[i] = off;
            const int c = cnt[i];
            for (int p = 0; p < c; p += SB) {
                ch_agent[nch] = i;
                ch_start[nch] = off + p;
                ch_len[nch]   = (c - p < SB) ? (c - p) : SB;
                ++nch;
            }
            off += c;
        }
        for (; nch < MAXCH; ++nch) ch_len[nch] = 0;
    }
    __syncthreads();
    if (t < 64) cnt[t] = 0;
    __syncthreads();
    const int pos = start[a] + atomicAdd(&cnt[a], 1);
    sorted[pos] = t;
}

// ---------------- K1: H = relu(X @ W1[a] + b1[a])  (256 -> 512) -------------
// grid (MAXCH chunks, 4 col-tiles of 128), block 256 = 64 col-pairs x 4 sgroups
extern "C" __global__ __launch_bounds__(256)
void k1_mlp1(const float* __restrict__ x, const float* __restrict__ W1,
             const float* __restrict__ b1,
             const int* __restrict__ sorted, const int* __restrict__ ch_agent,
             const int* __restrict__ ch_start, const int* __restrict__ ch_len,
             float* __restrict__ h_out)
{
    const int chunk = blockIdx.x;
    const int len = ch_len[chunk];
    if (len == 0) return;
    const int a  = ch_agent[chunk];
    const int cs = ch_start[chunk];
    const int t  = threadIdx.x;

    __shared__ float xsT[IN_DIM * PAD];   // x transposed [k][s], 20 KB
    __shared__ int sidS[SB];

    if (t < SB) sidS[t] = sorted[cs + (t < len ? t : len - 1)]; // pad=dup
    __syncthreads();
    #pragma unroll
    for (int s = 0; s < SB; ++s)
        xsT[t * PAD + s] = x[(size_t)sidS[s] * IN_DIM + t];     // coalesced rows
    __syncthreads();

    const int col = blockIdx.y * 128 + 2 * (t & 63);
    const int s0  = (t >> 6) * 4;
    const float* wp = W1 + (size_t)a * IN_DIM * HID_DIM + col;
    float accA[4] = {0.f, 0.f, 0.f, 0.f};
    float accB[4] = {0.f, 0.f, 0.f, 0.f};
    #pragma unroll 4
    for (int k = 0; k < IN_DIM; ++k) {
        const float2 w = *(const float2*)wp;  wp += HID_DIM;
        const float* xr = &xsT[k * PAD + s0];   // 16B-aligned broadcast
        #pragma unroll
        for (int j = 0; j < 4; ++j) {
            accA[j] = fmaf(xr[j], w.x, accA[j]);
            accB[j] = fmaf(xr[j], w.y, accB[j]);
        }
    }
    const float bA = b1[a * HID_DIM + col];
    const float bB = b1[a * HID_DIM + col + 1];
    #pragma unroll
    for (int j = 0; j < 4; ++j) {
        float2 v;
        v.x = fmaxf(accA[j] + bA, 0.f);
        v.y = fmaxf(accB[j] + bB, 0.f);
        *(float2*)(h_out + (size_t)sidS[s0 + j] * HID_DIM + col) = v; // dup-safe
    }
}

// ---------------- K2: OUT = H @ W2[a] + b2[a]; R = H @ rw[a] ----------------
// grid (MAXCH chunks, 2 col-tiles of 128), block 256; router on tile 0
extern "C" __global__ __launch_bounds__(256)
void k2_mlp2(const float* __restrict__ h, const float* __restrict__ W2,
             const float* __restrict__ b2, const float* __restrict__ rw,
             const int* __restrict__ sorted, const int* __restrict__ ch_agent,
             const int* __restrict__ ch_start, const int* __restrict__ ch_len,
             float* __restrict__ o_out, float* __restrict__ r_out)
{
    const int chunk = blockIdx.x;
    const int len = ch_len[chunk];
    if (len == 0) return;
    const int a  = ch_agent[chunk];
    const int cs = ch_start[chunk];
    const int t  = threadIdx.x;

    __shared__ float hsT[HID_DIM * PAD];  // h transposed [k][s], 40 KB
    __shared__ float red[256];
    __shared__ int sidS[SB];

    if (t < SB) sidS[t] = sorted[cs + (t < len ? t : len - 1)];
    __syncthreads();
    #pragma unroll
    for (int s = 0; s < SB; ++s) {
        const size_t row = (size_t)sidS[s] * HID_DIM;
        hsT[t * PAD + s]         = h[row + t];
        hsT[(t + 256) * PAD + s] = h[row + t + 256];
    }
    __syncthreads();

    const int col = blockIdx.y * 128 + 2 * (t & 63);
    const int s0  = (t >> 6) * 4;
    const float* wp = W2 + (size_t)a * HID_DIM * OUT_DIM + col;
    float accA[4] = {0.f, 0.f, 0.f, 0.f};
    float accB[4] = {0.f, 0.f, 0.f, 0.f};
    #pragma unroll 4
    for (int k = 0; k < HID_DIM; ++k) {
        const float2 w = *(const float2*)wp;  wp += OUT_DIM;
        const float* xr = &hsT[k * PAD + s0];
        #pragma unroll
        for (int j = 0; j < 4; ++j) {
            accA[j] = fmaf(xr[j], w.x, accA[j]);
            accB[j] = fmaf(xr[j], w.y, accB[j]);
        }
    }
    const float bA = b2[a * OUT_DIM + col];
    const float bB = b2[a * OUT_DIM + col + 1];
    #pragma unroll
    for (int j = 0; j < 4; ++j) {
        float2 v;
        v.x = accA[j] + bA;
        v.y = accB[j] + bB;
        *(float2*)(o_out + (size_t)sidS[s0 + j] * OUT_DIM + col) = v;
    }

    // ---- router: R[s][c] = sum_k h[s][k] * rw[a][k][c] ----
    if (blockIdx.y == 0) {            // block-uniform branch: barrier is safe
        const int s  = t >> 4;        // 0..15
        const int c  = (t >> 1) & 7;  // 0..7
        const int kh = t & 1;         // k half
        const float* rwa = rw + (size_t)a * HID_DIM * N_CHILD + c;
        const int k0 = kh * 256;
        float p = 0.f;
        for (int k = 0; k < 256; ++k)
            p = fmaf(hsT[(k0 + k) * PAD + s], rwa[(size_t)(k0 + k) * N_CHILD], p);
        red[t] = p;
        __syncthreads();
        if (!kh)
            r_out[(size_t)sidS[s] * N_CHILD + c] = red[t] + red[t + 1];
    }
}

extern "C" void kernel_launch(void* const* d_in, const int* in_sizes, int n_in,
                              void* d_out, int out_size, void* d_ws, size_t ws_size,
                              hipStream_t stream) {
    const float* x  = (const float*)d_in[0];
    const float* W1 = (const float*)d_in[1];
    const float* b1 = (const float*)d_in[2];
    const float* W2 = (const float*)d_in[3];
    const float* b2 = (const float*)d_in[4];
    const float* rw = (const float*)d_in[5];
    const int* raw  = (const int*)d_in[6];

    int* ws       = (int*)d_ws;
    int* sorted   = ws;            // [1024]
    int* ch_agent = ws + 1024;     // [128]
    int* ch_start = ws + 1152;     // [128]
    int* ch_len   = ws + 1280;     // [128]

    float* out   = (float*)d_out;
    float* h_out = out;                                   // [B, HID]
    float* o_out = h_out + (size_t)BATCH * HID_DIM;       // [B, OUT]
    float* r_out = o_out + (size_t)BATCH * OUT_DIM;       // [B, C]

    hipLaunchKernelGGL(prep_sort, dim3(1), dim3(1024), 0, stream,
                       raw, sorted, ch_agent, ch_start, ch_len);
    hipLaunchKernelGGL(k1_mlp1, dim3(MAXCH, 4), dim3(256), 0, stream,
                       x, W1, b1, sorted, ch_agent, ch_start, ch_len, h_out);
    hipLaunchKernelGGL(k2_mlp2, dim3(MAXCH, 2), dim3(256), 0, stream,
                       h_out, W2, b2, rw, sorted, ch_agent, ch_start, ch_len,
                       o_out, r_out);
}

// Round 6
// 155.281 us; speedup vs baseline: 1.2814x; 1.2814x over previous
//
#include <hip/hip_runtime.h>

#define IN_DIM   256
#define HID_DIM  512
#define OUT_DIM  256
#define N_CHILD  8
#define BATCH    1024

#define SB    16   // samples per chunk
#define PAD   20   // [k][s] LDS row stride (floats): 16B-aligned, odd-ish banks
#define MAXCH 128  // static bound: sum ceil(n_a/SB) <= (1024+64*15)/16 = 124
#define CK    128  // K rows staged per pass

// ---------------- prep: counting-sort samples by agent, build chunk list ----
// agent_indices may be int32 or int64 (jax_enable_x64): view as int32; if any
// odd word != 0 it's int32, else int64 (odd slots are zero high words).
extern "C" __global__ __launch_bounds__(1024)
void prep_sort(const int* __restrict__ raw, int* __restrict__ sorted,
               int* __restrict__ ch_agent, int* __restrict__ ch_start,
               int* __restrict__ ch_len)
{
    __shared__ int cnt[64], start[64];
    __shared__ int is32;
    const int t = threadIdx.x;
    if (t < 64) cnt[t] = 0;
    if (t == 0) is32 = 0;
    __syncthreads();
    if (raw[2 * (t & 511) + 1] != 0) is32 = 1;   // benign shared race
    __syncthreads();
    const int a = (is32 ? raw[t] : raw[2 * t]) & 63;
    atomicAdd(&cnt[a], 1);
    __syncthreads();
    if (t == 0) {
        int off = 0, nch = 0;
        for (int i = 0; i < 64; ++i) {
            start[i] = off;
            const int c = cnt[i];
            for (int p = 0; p < c; p += SB) {
                ch_agent[nch] = i;
                ch_start[nch] = off + p;
                ch_len[nch]   = (c - p < SB) ? (c - p) : SB;
                ++nch;
            }
            off += c;
        }
        for (; nch < MAXCH; ++nch) ch_len[nch] = 0;
    }
    __syncthreads();
    if (t < 64) cnt[t] = 0;
    __syncthreads();
    const int pos = start[a] + atomicAdd(&cnt[a], 1);
    sorted[pos] = t;
}

// ---------------- K1: H = relu(X @ W1[a] + b1[a])  (256 -> 512) -------------
// grid (MAXCH, 8 tiles of 64 cols), 256 thr. LDS-staged weights, reg tiles.
// thread: cg=t&15 (4 cols), sg=(t>>4)&1 (8 samples), kq=t>>5 (8-way K split).
extern "C" __global__ __launch_bounds__(256)
void k1_mlp1(const float* __restrict__ x, const float* __restrict__ W1,
             const float* __restrict__ b1,
             const int* __restrict__ sorted, const int* __restrict__ ch_agent,
             const int* __restrict__ ch_start, const int* __restrict__ ch_len,
             float* __restrict__ h_out)
{
    const int chunk = blockIdx.x;
    const int len = ch_len[chunk];
    if (len == 0) return;
    const int a  = ch_agent[chunk];
    const int cs = ch_start[chunk];
    const int t  = threadIdx.x;
    const int bcol = blockIdx.y * 64;

    __shared__ float xsT[IN_DIM * PAD];   // 20 KB, [k][s], all 256 k rows
    __shared__ float wS[CK * 64];         // 32 KB, [k][c]; reused as scratch
    __shared__ int   sidS[SB];

    if (t < SB) sidS[t] = sorted[cs + (t < len ? t : len - 1)]; // pad=dup
    __syncthreads();
    #pragma unroll
    for (int s = 0; s < SB; ++s)
        xsT[t * PAD + s] = x[(size_t)sidS[s] * IN_DIM + t];     // coalesced

    const int cg = t & 15;
    const int sg = (t >> 4) & 1;
    const int kq = t >> 5;
    const float* Wb = W1 + (size_t)a * IN_DIM * HID_DIM + bcol;

    float acc[4][8];
    #pragma unroll
    for (int j = 0; j < 4; ++j)
        #pragma unroll
        for (int i = 0; i < 8; ++i) acc[j][i] = 0.f;

    for (int p = 0; p < IN_DIM / CK; ++p) {        // 2 passes
        const int k0 = p * CK;
        __syncthreads();   // wS free (also covers xsT stage at p==0)
        #pragma unroll
        for (int i = 0; i < 8; ++i) {              // stage 32 KB of W1 tile
            const int id  = t + i * 256;
            const int row = id >> 4;
            const int c4  = (id & 15) * 4;
            const float4 w = *(const float4*)(Wb + (size_t)(k0 + row) * HID_DIM + c4);
            *(float4*)(&wS[row * 64 + c4]) = w;
        }
        __syncthreads();
        #pragma unroll 4
        for (int i = 0; i < CK / 8; ++i) {         // 16 iters/thread
            const int kl = kq * (CK / 8) + i;
            const float4 w  = *(const float4*)(&wS[kl * 64 + cg * 4]);
            const float4 xa = *(const float4*)(&xsT[(k0 + kl) * PAD + sg * 8]);
            const float4 xb = *(const float4*)(&xsT[(k0 + kl) * PAD + sg * 8 + 4]);
            const float wv[4] = {w.x, w.y, w.z, w.w};
            const float xv[8] = {xa.x, xa.y, xa.z, xa.w, xb.x, xb.y, xb.z, xb.w};
            #pragma unroll
            for (int j = 0; j < 4; ++j)
                #pragma unroll
                for (int q = 0; q < 8; ++q)
                    acc[j][q] = fmaf(wv[j], xv[q], acc[j][q]);
        }
    }

    // ---- 8-way kq reduction via LDS scratch (reuse wS: 8192 floats) ----
    __syncthreads();
    float* sc = wS;
    #pragma unroll
    for (int j = 0; j < 4; ++j)
        #pragma unroll
        for (int i = 0; i < 8; ++i)
            sc[t * 32 + j * 8 + i] = acc[j][i];
    __syncthreads();
    const int c = t & 63;
    #pragma unroll
    for (int u = 0; u < 4; ++u) {
        const int s = (t >> 6) + u * 4;
        float v = 0.f;
        #pragma unroll
        for (int q = 0; q < 8; ++q)
            v += sc[((c >> 2) + ((s >> 3) << 4) + (q << 5)) * 32
                    + (c & 3) * 8 + (s & 7)];
        v = fmaxf(v + b1[a * HID_DIM + bcol + c], 0.f);
        h_out[(size_t)sidS[s] * HID_DIM + bcol + c] = v;   // dup-safe
    }
}

// ---------------- K2: OUT = H @ W2[a] + b2[a]  (512 -> 256) -----------------
// grid (MAXCH, 4 tiles of 64 cols), 256 thr. Same structure, 4 K-passes,
// h staged per pass.
extern "C" __global__ __launch_bounds__(256)
void k2_mlp2(const float* __restrict__ h, const float* __restrict__ W2,
             const float* __restrict__ b2,
             const int* __restrict__ sorted, const int* __restrict__ ch_agent,
             const int* __restrict__ ch_start, const int* __restrict__ ch_len,
             float* __restrict__ o_out)
{
    const int chunk = blockIdx.x;
    const int len = ch_len[chunk];
    if (len == 0) return;
    const int a  = ch_agent[chunk];
    const int cs = ch_start[chunk];
    const int t  = threadIdx.x;
    const int bcol = blockIdx.y * 64;

    __shared__ float hsT[CK * PAD];       // 10 KB, current-pass h rows
    __shared__ float wS[CK * 64];         // 32 KB; reused as scratch
    __shared__ int   sidS[SB];

    if (t < SB) sidS[t] = sorted[cs + (t < len ? t : len - 1)];
    __syncthreads();

    const int cg = t & 15;
    const int sg = (t >> 4) & 1;
    const int kq = t >> 5;
    const float* Wb = W2 + (size_t)a * HID_DIM * OUT_DIM + bcol;

    float acc[4][8];
    #pragma unroll
    for (int j = 0; j < 4; ++j)
        #pragma unroll
        for (int i = 0; i < 8; ++i) acc[j][i] = 0.f;

    for (int p = 0; p < HID_DIM / CK; ++p) {       // 4 passes
        const int k0 = p * CK;
        __syncthreads();   // hsT/wS free
        {
            const int row = t & 127;
            const int sh  = t >> 7;
            #pragma unroll
            for (int i = 0; i < 8; ++i) {          // stage h rows
                const int s = sh * 8 + i;
                hsT[row * PAD + s] = h[(size_t)sidS[s] * HID_DIM + k0 + row];
            }
        }
        #pragma unroll
        for (int i = 0; i < 8; ++i) {              // stage 32 KB of W2 tile
            const int id  = t + i * 256;
            const int row = id >> 4;
            const int c4  = (id & 15) * 4;
            const float4 w = *(const float4*)(Wb + (size_t)(k0 + row) * OUT_DIM + c4);
            *(float4*)(&wS[row * 64 + c4]) = w;
        }
        __syncthreads();
        #pragma unroll 4
        for (int i = 0; i < CK / 8; ++i) {         // 16 iters/thread
            const int kl = kq * (CK / 8) + i;
            const float4 w  = *(const float4*)(&wS[kl * 64 + cg * 4]);
            const float4 xa = *(const float4*)(&hsT[kl * PAD + sg * 8]);
            const float4 xb = *(const float4*)(&hsT[kl * PAD + sg * 8 + 4]);
            const float wv[4] = {w.x, w.y, w.z, w.w};
            const float xv[8] = {xa.x, xa.y, xa.z, xa.w, xb.x, xb.y, xb.z, xb.w};
            #pragma unroll
            for (int j = 0; j < 4; ++j)
                #pragma unroll
                for (int q = 0; q < 8; ++q)
                    acc[j][q] = fmaf(wv[j], xv[q], acc[j][q]);
        }
    }

    __syncthreads();
    float* sc = wS;
    #pragma unroll
    for (int j = 0; j < 4; ++j)
        #pragma unroll
        for (int i = 0; i < 8; ++i)
            sc[t * 32 + j * 8 + i] = acc[j][i];
    __syncthreads();
    const int c = t & 63;
    #pragma unroll
    for (int u = 0; u < 4; ++u) {
        const int s = (t >> 6) + u * 4;
        float v = 0.f;
        #pragma unroll
        for (int q = 0; q < 8; ++q)
            v += sc[((c >> 2) + ((s >> 3) << 4) + (q << 5)) * 32
                    + (c & 3) * 8 + (s & 7)];
        v += b2[a * OUT_DIM + bcol + c];
        o_out[(size_t)sidS[s] * OUT_DIM + bcol + c] = v;
    }
}

// ---------------- K3: R = H @ rw[a]  (512 -> 8) -----------------------------
// grid MAXCH, 256 thr: t = c + s*8 + kq*128 (kq 2-way K split).
extern "C" __global__ __launch_bounds__(256)
void k3_router(const float* __restrict__ h, const float* __restrict__ rw,
               const int* __restrict__ sorted, const int* __restrict__ ch_agent,
               const int* __restrict__ ch_start, const int* __restrict__ ch_len,
               float* __restrict__ r_out)
{
    const int chunk = blockIdx.x;
    const int len = ch_len[chunk];
    if (len == 0) return;
    const int a  = ch_agent[chunk];
    const int cs = ch_start[chunk];
    const int t  = threadIdx.x;

    __shared__ float sc[256];
    __shared__ int   sidS[SB];
    if (t < SB) sidS[t] = sorted[cs + (t < len ? t : len - 1)];
    __syncthreads();

    const int c  = t & 7;
    const int s  = (t >> 3) & 15;
    const int kq = t >> 7;                 // 0..1
    const float* hv = h  + (size_t)sidS[s] * HID_DIM + kq * 256;
    const float* rv = rw + (size_t)a * HID_DIM * N_CHILD
                          + (size_t)kq * 256 * N_CHILD + c;
    float p = 0.f;
    #pragma unroll 8
    for (int k = 0; k < 256; ++k)
        p = fmaf(hv[k], rv[(size_t)k * N_CHILD], p);
    sc[t] = p;
    __syncthreads();
    if (t < 128)
        r_out[(size_t)sidS[s] * N_CHILD + c] = sc[t] + sc[t + 128];
}

extern "C" void kernel_launch(void* const* d_in, const int* in_sizes, int n_in,
                              void* d_out, int out_size, void* d_ws, size_t ws_size,
                              hipStream_t stream) {
    const float* x  = (const float*)d_in[0];
    const float* W1 = (const float*)d_in[1];
    const float* b1 = (const float*)d_in[2];
    const float* W2 = (const float*)d_in[3];
    const float* b2 = (const float*)d_in[4];
    const float* rw = (const float*)d_in[5];
    const int* raw  = (const int*)d_in[6];

    int* ws       = (int*)d_ws;
    int* sorted   = ws;            // [1024]
    int* ch_agent = ws + 1024;     // [128]
    int* ch_start = ws + 1152;     // [128]
    int* ch_len   = ws + 1280;     // [128]

    float* out   = (float*)d_out;
    float* h_out = out;                                   // [B, HID]
    float* o_out = h_out + (size_t)BATCH * HID_DIM;       // [B, OUT]
    float* r_out = o_out + (size_t)BATCH * OUT_DIM;       // [B, C]

    hipLaunchKernelGGL(prep_sort, dim3(1), dim3(1024), 0, stream,
                       raw, sorted, ch_agent, ch_start, ch_len);
    hipLaunchKernelGGL(k1_mlp1, dim3(MAXCH, 8), dim3(256), 0, stream,
                       x, W1, b1, sorted, ch_agent, ch_start, ch_len, h_out);
    hipLaunchKernelGGL(k2_mlp2, dim3(MAXCH, 4), dim3(256), 0, stream,
                       h_out, W2, b2, sorted, ch_agent, ch_start, ch_len, o_out);
    hipLaunchKernelGGL(k3_router, dim3(MAXCH), dim3(256), 0, stream,
                       h_out, rw, sorted, ch_agent, ch_start, ch_len, r_out);
}